// Round 6
// baseline (576.471 us; speedup 1.0000x reference)
//
#include <hip/hip_runtime.h>
#include <math.h>

#define NNODES 200000
#define NG 1000
#define NPG 200
#define KNN 5
#define MD 128
#define S6 (1.0f / 6.0f)
#define NPAD 208  // 13 M-tiles of 16

typedef short short8 __attribute__((ext_vector_type(8)));
typedef float floatx4 __attribute__((ext_vector_type(4)));

// RNE bf16 split-pack: returns (bf16(v) << 16) | bf16(v - bf16(v))
__device__ __forceinline__ unsigned splitpack(float f) {
  unsigned u = __float_as_uint(f);
  unsigned hb = (u + 0x7fffu + ((u >> 16) & 1u)) >> 16;
  float hf = __uint_as_float(hb << 16);
  float r = f - hf;
  unsigned v = __float_as_uint(r);
  unsigned lb = (v + 0x7fffu + ((v >> 16) & 1u)) >> 16;
  return (hb << 16) | (lb & 0xffffu);
}

// reconstruct fp32 from packed split word: hi + lo
__device__ __forceinline__ float upk(unsigned w) {
  return __uint_as_float(w & 0xffff0000u) + __uint_as_float(w << 16);
}

__device__ __forceinline__ void unpack8(int4 u, int4 v, short8* hi, short8* lo) {
  unsigned w[8] = {(unsigned)u.x, (unsigned)u.y, (unsigned)u.z, (unsigned)u.w,
                   (unsigned)v.x, (unsigned)v.y, (unsigned)v.z, (unsigned)v.w};
  short8 h, l;
#pragma unroll
  for (int i = 0; i < 8; i++) {
    h[i] = (short)(w[i] >> 16);
    l[i] = (short)(w[i] & 0xffffu);
  }
  *hi = h;
  *lo = l;
}

// ---------------- kNN: one block per graph (validated R1..R5) ----------------
__global__ __launch_bounds__(256) void knn_kernel(const float* __restrict__ pos,
                                                  int* __restrict__ knn) {
  __shared__ float sp[NPG * 3];
  int g = blockIdx.x;
  int t = threadIdx.x;
  for (int i = t; i < NPG * 3; i += 256) sp[i] = pos[(size_t)g * NPG * 3 + i];
  __syncthreads();
  if (t < NPG) {
    float x = sp[t * 3 + 0], y = sp[t * 3 + 1], z = sp[t * 3 + 2];
    float bd[KNN];
    int bi[KNN];
#pragma unroll
    for (int k = 0; k < KNN; k++) { bd[k] = 3.0e38f; bi[k] = 0; }
    for (int j = 0; j < NPG; j++) {
      if (j == t) continue;
      float dx = __fsub_rn(x, sp[j * 3 + 0]);
      float dy = __fsub_rn(y, sp[j * 3 + 1]);
      float dz = __fsub_rn(z, sp[j * 3 + 2]);
      float d2 = __fadd_rn(__fadd_rn(__fmul_rn(dx, dx), __fmul_rn(dy, dy)),
                           __fmul_rn(dz, dz));
      if (d2 < bd[KNN - 1]) {
        bd[KNN - 1] = d2; bi[KNN - 1] = j;
#pragma unroll
        for (int k = KNN - 1; k > 0; k--) {
          if (bd[k] < bd[k - 1]) {
            float td = bd[k]; bd[k] = bd[k - 1]; bd[k - 1] = td;
            int ti = bi[k]; bi[k] = bi[k - 1]; bi[k - 1] = ti;
          }
        }
      }
    }
#pragma unroll
    for (int k = 0; k < KNN; k++)
      knn[((size_t)g * NPG + t) * KNN + k] = g * NPG + bi[k];
  }
}

// ---------------- embW0 = emb @ W0 (100x128 @ 128x128) ----------------
__global__ __launch_bounds__(256) void emb_gemm_kernel(const float* __restrict__ emb,
                                                       const float* __restrict__ W,
                                                       float* __restrict__ embW) {
  int idx = blockIdx.x * 256 + threadIdx.x;  // 12800 total
  int r = idx >> 7, c = idx & 127;
  float a = 0.0f;
  for (int k = 0; k < MD; k++) a += emb[r * MD + k] * W[k * MD + c];
  embW[idx] = a;
}

// ---------------- pre-pack W1,W2 into MFMA B-fragment layout (validated R5) ----
// [layer(2)][T(8)][c(4)][lane(64)][j(8)]: lane holds B[k=32c+8q+j][n=16T+m].
__global__ __launch_bounds__(256) void prepack_kernel(const float* __restrict__ convW,
                                                      unsigned short* __restrict__ WhiF,
                                                      unsigned short* __restrict__ WloF) {
  int idx = blockIdx.x * 256 + threadIdx.x;  // 0..4095
  int lane = idx & 63;
  int c = (idx >> 6) & 3;
  int T = (idx >> 8) & 7;
  int l = idx >> 11;  // 0..1 -> W1, W2
  const float* W = convW + (size_t)(l + 1) * MD * MD;
  int m = lane & 15, q = lane >> 4;
  int n = 16 * T + m;
  unsigned short hi[8], lo[8];
#pragma unroll
  for (int j = 0; j < 8; j++) {
    int k = 32 * c + 8 * q + j;
    unsigned p = splitpack(W[(size_t)k * MD + n]);
    hi[j] = (unsigned short)(p >> 16);
    lo[j] = (unsigned short)(p & 0xffffu);
  }
  *(short8*)(WhiF + (size_t)idx * 8) = *(short8*)hi;
  *(short8*)(WloF + (size_t)idx * 8) = *(short8*)lo;
}

// ---------------- mega: whole network per graph, x resident in LDS -----------
// 1024 thr (16 waves). Ax[208][128] packed split words, XOR-swizzled 4-word
// granules by (row&7) (layout validated R5). Wave wv: mg=wv>>1 M-group
// (M-tiles mg, mg+8), nh=wv&1 col half. B-frags in VGPRs from prepack arrays.
__global__ __launch_bounds__(1024) void mega_kernel(
    const int* __restrict__ z, const int* __restrict__ knn,
    const float* __restrict__ embW, const float* __restrict__ convb,
    const unsigned short* __restrict__ WhiF, const unsigned short* __restrict__ WloF,
    const float* __restrict__ rW1, const float* __restrict__ rb1,
    const float* __restrict__ rW2, const float* __restrict__ rb2,
    const float* __restrict__ rW3, const float* __restrict__ rb3,
    float* __restrict__ out) {
  __shared__ unsigned Ax[NPAD * 128];  // 106,496 B
  __shared__ int kl[NPG * KNN];        // 4,000 B (global neighbor ids)
  __shared__ int zi[NPG * 6];          // 4,800 B (z codes: self + 5 neighbors)
  __shared__ float red[8 * 128];       // 4,096 B
  __shared__ float pooled[128];
  __shared__ float h1s[64];
  __shared__ float h2s[32];

  const int g = blockIdx.x;
  const int tid = threadIdx.x;

  // ---- phase 0: stage knn + z codes ----
  if (tid < 250) ((int4*)kl)[tid] = ((const int4*)(knn + (size_t)g * NPG * KNN))[tid];
  __syncthreads();
  for (int idx = tid; idx < NPG * 6; idx += 1024) {
    int n = idx / 6, s = idx - 6 * n;
    int node = (s == 0) ? (g * NPG + n) : kl[n * KNN + (s - 1)];
    zi[idx] = z[node];
  }
  __syncthreads();

  // ---- phase 1: x1 = relu(s6*(sum embW rows) + b0), packed into Ax ----
  {
    const float4* G4 = (const float4*)embW;
    const float4* B40 = (const float4*)convb;
#pragma unroll
    for (int it = 0; it < 7; it++) {
      int idx = tid + 1024 * it;
      if (idx < NPAD * 32) {
        int n = idx >> 5, kq = idx & 31;
        int4 pk = make_int4(0, 0, 0, 0);
        if (n < NPG) {
          const int* zz = zi + n * 6;
          float4 s = G4[(size_t)zz[0] * 32 + kq];
          float4 t1 = G4[(size_t)zz[1] * 32 + kq]; s.x += t1.x; s.y += t1.y; s.z += t1.z; s.w += t1.w;
          float4 t2 = G4[(size_t)zz[2] * 32 + kq]; s.x += t2.x; s.y += t2.y; s.z += t2.z; s.w += t2.w;
          float4 t3 = G4[(size_t)zz[3] * 32 + kq]; s.x += t3.x; s.y += t3.y; s.z += t3.z; s.w += t3.w;
          float4 t4 = G4[(size_t)zz[4] * 32 + kq]; s.x += t4.x; s.y += t4.y; s.z += t4.z; s.w += t4.w;
          float4 t5 = G4[(size_t)zz[5] * 32 + kq]; s.x += t5.x; s.y += t5.y; s.z += t5.z; s.w += t5.w;
          float4 bb = B40[kq];
          pk.x = (int)splitpack(fmaxf(s.x * S6 + bb.x, 0.0f));
          pk.y = (int)splitpack(fmaxf(s.y * S6 + bb.y, 0.0f));
          pk.z = (int)splitpack(fmaxf(s.z * S6 + bb.z, 0.0f));
          pk.w = (int)splitpack(fmaxf(s.w * S6 + bb.w, 0.0f));
        }
        *(int4*)(Ax + n * 128 + ((kq ^ (n & 7)) << 2)) = pk;
      }
    }
  }
  __syncthreads();

  const int lane = tid & 63;
  const int wv = tid >> 6;  // 0..15
  const int m = lane & 15;
  const int q = lane >> 4;
  const int mg = wv >> 1;   // 0..7
  const int nh = wv & 1;    // col half

  // ---- phase 2: two GCN layers fully in LDS ----
  for (int l = 0; l < 2; l++) {
    const unsigned short* Whi = WhiF + (size_t)l * 16384;
    const unsigned short* Wlo = WloF + (size_t)l * 16384;
    // B fragments in VGPRs (L2-resident)
    short8 bhi[4][4], blo[4][4];
#pragma unroll
    for (int t = 0; t < 4; t++)
#pragma unroll
      for (int c = 0; c < 4; c++) {
        int T = nh * 4 + t;
        size_t off = ((size_t)(T * 4 + c) * 64 + lane) * 8;
        bhi[t][c] = *(const short8*)(Whi + off);
        blo[t][c] = *(const short8*)(Wlo + off);
      }
    // GEMM: M-tiles mg and mg+8 (if < 13)
    floatx4 Cacc[2][4];
#pragma unroll
    for (int u = 0; u < 2; u++) {
      int mt = mg + 8 * u;
      if (mt < 13) {
        short8 ahi[4], alo[4];
        int r = mt * 16 + m;
        const unsigned* base = Ax + r * 128;
        int sw = r & 7;
#pragma unroll
        for (int c = 0; c < 4; c++) {
          int g1 = (8 * c + 2 * q) ^ sw;
          int g2 = (8 * c + 2 * q + 1) ^ sw;
          int4 uu = *(const int4*)(base + (g1 << 2));
          int4 vv = *(const int4*)(base + (g2 << 2));
          unpack8(uu, vv, &ahi[c], &alo[c]);
        }
#pragma unroll
        for (int t = 0; t < 4; t++) {
          floatx4 acc = (floatx4){0.f, 0.f, 0.f, 0.f};
#pragma unroll
          for (int c = 0; c < 4; c++) {
            acc = __builtin_amdgcn_mfma_f32_16x16x32_bf16(ahi[c], bhi[t][c], acc, 0, 0, 0);
            acc = __builtin_amdgcn_mfma_f32_16x16x32_bf16(ahi[c], blo[t][c], acc, 0, 0, 0);
            acc = __builtin_amdgcn_mfma_f32_16x16x32_bf16(alo[c], bhi[t][c], acc, 0, 0, 0);
          }
          Cacc[u][t] = acc;
        }
      }
    }
    __syncthreads();  // all x_l reads done
    // write h packed into Ax (C/D layout: col=16T+m, row=16mt+4q+reg)
#pragma unroll
    for (int u = 0; u < 2; u++) {
      int mt = mg + 8 * u;
      if (mt < 13) {
#pragma unroll
        for (int t = 0; t < 4; t++) {
          int col = nh * 64 + 16 * t + m;
          int colg = col >> 2, cw = col & 3;
#pragma unroll
          for (int reg = 0; reg < 4; reg++) {
            int row = mt * 16 + 4 * q + reg;
            if (row < NPG)
              Ax[row * 128 + ((colg ^ (row & 7)) << 2) + cw] = splitpack(Cacc[u][t][reg]);
          }
        }
      }
    }
    __syncthreads();
    // agg: x_{l+1} = relu(s6*(h self+5 nbrs) + b_{l+1}), staged in regs
    const float4* Bl = (const float4*)(convb + (size_t)(l + 1) * MD);
    int4 xa[7];
#pragma unroll
    for (int it = 0; it < 7; it++) {
      int idx = tid + 1024 * it;
      if (idx < NPG * 32) {
        int n = idx >> 5, kq = idx & 31;
        const int* kn = kl + n * KNN;
        int rr[6];
        rr[0] = n;
        rr[1] = kn[0] - g * NPG; rr[2] = kn[1] - g * NPG; rr[3] = kn[2] - g * NPG;
        rr[4] = kn[3] - g * NPG; rr[5] = kn[4] - g * NPG;
        float4 s = make_float4(0.f, 0.f, 0.f, 0.f);
#pragma unroll
        for (int e = 0; e < 6; e++) {
          int r = rr[e];
          int4 w = *(const int4*)(Ax + r * 128 + ((kq ^ (r & 7)) << 2));
          s.x += upk((unsigned)w.x);
          s.y += upk((unsigned)w.y);
          s.z += upk((unsigned)w.z);
          s.w += upk((unsigned)w.w);
        }
        float4 bb = Bl[kq];
        int4 pk;
        pk.x = (int)splitpack(fmaxf(s.x * S6 + bb.x, 0.0f));
        pk.y = (int)splitpack(fmaxf(s.y * S6 + bb.y, 0.0f));
        pk.z = (int)splitpack(fmaxf(s.z * S6 + bb.z, 0.0f));
        pk.w = (int)splitpack(fmaxf(s.w * S6 + bb.w, 0.0f));
        xa[it] = pk;
      }
    }
    __syncthreads();  // all h reads done
#pragma unroll
    for (int it = 0; it < 7; it++) {
      int idx = tid + 1024 * it;
      if (idx < NPG * 32) {
        int n = idx >> 5, kq = idx & 31;
        *(int4*)(Ax + n * 128 + ((kq ^ (n & 7)) << 2)) = xa[it];
      }
    }
    __syncthreads();
  }

  // ---- phase 3: mean pool + MLP ----
  {
    int col = tid & 127, grp = tid >> 7;  // 8 groups x 25 rows
    int colg = col >> 2, cw = col & 3;
    float s = 0.0f;
    for (int j = 0; j < 25; j++) {
      int n = grp * 25 + j;
      s += upk(Ax[n * 128 + ((colg ^ (n & 7)) << 2) + cw]);
    }
    red[grp * 128 + col] = s;
  }
  __syncthreads();
  if (tid < 128) {
    float p = 0.0f;
#pragma unroll
    for (int r = 0; r < 8; r++) p += red[r * 128 + tid];
    pooled[tid] = p / (float)NPG;
  }
  __syncthreads();
  if (tid < 64) {
    float a = rb1[tid];
    for (int c = 0; c < 128; c++) a += pooled[c] * rW1[c * 64 + tid];
    h1s[tid] = fmaxf(a, 0.0f);
  }
  __syncthreads();
  if (tid < 32) {
    float a = rb2[tid];
    for (int c = 0; c < 64; c++) a += h1s[c] * rW2[c * 32 + tid];
    h2s[tid] = fmaxf(a, 0.0f);
  }
  __syncthreads();
  if (tid == 0) {
    float a = rb3[0];
    for (int c = 0; c < 32; c++) a += h2s[c] * rW3[c];
    out[g] = a;
  }
}

extern "C" void kernel_launch(void* const* d_in, const int* in_sizes, int n_in,
                              void* d_out, int out_size, void* d_ws, size_t ws_size,
                              hipStream_t stream) {
  const int* z = (const int*)d_in[0];
  const float* pos = (const float*)d_in[1];
  const float* emb = (const float*)d_in[3];
  const float* convW = (const float*)d_in[4];  // [3][128][128]
  const float* convb = (const float*)d_in[5];  // [3][128]
  const float* rW1 = (const float*)d_in[6];
  const float* rb1 = (const float*)d_in[7];
  const float* rW2 = (const float*)d_in[8];
  const float* rb2 = (const float*)d_in[9];
  const float* rW3 = (const float*)d_in[10];
  const float* rb3 = (const float*)d_in[11];
  float* out = (float*)d_out;

  char* ws = (char*)d_ws;
  int* knn = (int*)ws;                                   // 4,000,000 B
  float* embW = (float*)(ws + 4000000);                  // 51,200 B
  unsigned short* WhiF = (unsigned short*)(ws + 4000000 + 51200);  // 65,536 B
  unsigned short* WloF = WhiF + 32768;                   // 65,536 B

  knn_kernel<<<NG, 256, 0, stream>>>(pos, knn);
  emb_gemm_kernel<<<50, 256, 0, stream>>>(emb, convW, embW);
  prepack_kernel<<<16, 256, 0, stream>>>(convW, WhiF, WloF);
  mega_kernel<<<NG, 1024, 0, stream>>>(z, knn, embW, convb, WhiF, WloF, rW1,
                                       rb1, rW2, rb2, rW3, rb3, out);
}